// Round 4
// baseline (482.358 us; speedup 1.0000x reference)
//
#include <hip/hip_runtime.h>
#include <hip/hip_bf16.h>

typedef unsigned short u16;
typedef unsigned int u32;
typedef __attribute__((ext_vector_type(8))) short short8;
typedef __attribute__((ext_vector_type(4))) float f32x4;

#define NN 8192
#define KIN 256
#define FOUT 128
#define SPLITS 8
#define KPER (NN / SPLITS)   // 1024
#define BK 64
#define ITERS (KPER / BK)    // 16
#define L2E 1.4426950408889634f

__device__ __forceinline__ float exp2fast(float x) { return __builtin_amdgcn_exp2f(x); }

__device__ __forceinline__ u16 f2bf(float f) {
    u32 u = __float_as_uint(f);
    u32 r = ((u >> 16) & 1u) + 0x7fffu;
    return (u16)((u + r) >> 16);
}
__device__ __forceinline__ u32 fkey(float f) {
    u32 b = __float_as_uint(f);
    return (b & 0x80000000u) ? ~b : (b | 0x80000000u);
}
__device__ __forceinline__ float funkey(u32 k) {
    u32 b = (k & 0x80000000u) ? (k & 0x7fffffffu) : ~k;
    return __uint_as_float(b);
}

// ---------------- K1: Wh = h@W (fp32 acc), Whbt (bf16 transposed), src/dst, gmax(dst)
__global__ __launch_bounds__(256) void k1_wh(
    const float* __restrict__ h, const float* __restrict__ W, const float* __restrict__ a,
    u16* __restrict__ whbt,
    float* __restrict__ src, float* __restrict__ dst, u32* __restrict__ gmaxk)
{
    __shared__ float hT[64][36];     // transposed h tile [k][r]
    __shared__ u16   lt[128][40];    // bf16 Wh^T tile [n][m], stride 40 u16 = 80B (16B mult)
    __shared__ float sd[32][2];      // per-row (src,dst) partials
    const int t  = threadIdx.x;
    const int m0 = blockIdx.x * 32;
    const int rq = t >> 5, cq = t & 31;

    float acc[4][4];
#pragma unroll
    for (int i = 0; i < 4; i++)
#pragma unroll
        for (int j = 0; j < 4; j++) acc[i][j] = 0.f;
    if (t < 64) sd[t >> 1][t & 1] = 0.f;

    for (int kt = 0; kt < KIN; kt += 64) {
        __syncthreads();
#pragma unroll
        for (int s2 = 0; s2 < 2; s2++) {
            int f = s2 * 256 + t;
            int r = f >> 4, kc = (f & 15) * 4;
            float4 hv = *(const float4*)(h + (size_t)(m0 + r) * KIN + kt + kc);
            hT[kc + 0][r] = hv.x; hT[kc + 1][r] = hv.y;
            hT[kc + 2][r] = hv.z; hT[kc + 3][r] = hv.w;
        }
        __syncthreads();
        for (int k = 0; k < 64; k++) {
            float4 wv = *(const float4*)(W + (size_t)(kt + k) * FOUT + cq * 4);
            float h0 = hT[k][rq * 4 + 0], h1 = hT[k][rq * 4 + 1];
            float h2 = hT[k][rq * 4 + 2], h3 = hT[k][rq * 4 + 3];
            acc[0][0] += h0 * wv.x; acc[0][1] += h0 * wv.y; acc[0][2] += h0 * wv.z; acc[0][3] += h0 * wv.w;
            acc[1][0] += h1 * wv.x; acc[1][1] += h1 * wv.y; acc[1][2] += h1 * wv.z; acc[1][3] += h1 * wv.w;
            acc[2][0] += h2 * wv.x; acc[2][1] += h2 * wv.y; acc[2][2] += h2 * wv.z; acc[2][3] += h2 * wv.w;
            acc[3][0] += h3 * wv.x; acc[3][1] += h3 * wv.y; acc[3][2] += h3 * wv.z; acc[3][3] += h3 * wv.w;
        }
    }
    // epilogue: bf16 transpose tile into LDS, src/dst partials
#pragma unroll
    for (int i = 0; i < 4; i++) {
        float sp = 0.f, dp = 0.f;
#pragma unroll
        for (int j = 0; j < 4; j++) {
            sp += acc[i][j] * a[cq * 4 + j];
            dp += acc[i][j] * a[FOUT + cq * 4 + j];
            lt[cq * 4 + j][rq * 4 + i] = f2bf(acc[i][j]);
        }
        atomicAdd(&sd[rq * 4 + i][0], sp);
        atomicAdd(&sd[rq * 4 + i][1], dp);
    }
    __syncthreads();
    if (t < 32) { src[m0 + t] = sd[t][0]; dst[m0 + t] = sd[t][1]; }
    if (t < 64) {
        float v = (t < 32) ? sd[t][1] : -3.0e38f;
#pragma unroll
        for (int off = 32; off >= 1; off >>= 1) v = fmaxf(v, __shfl_down(v, off));
        if (t == 0) atomicMax(gmaxk, fkey(v));
    }
    // coalesced bf16 transposed write: ALL 128 n-rows x 32 m-cols (512 uint4 = 2 per thread)
#pragma unroll
    for (int s2 = 0; s2 < 2; s2++) {
        int f = s2 * 256 + t;        // 0..511
        int n = f >> 2;              // 0..127
        int q = (f & 3) * 8;         // 0,8,16,24
        uint4 v = *(const uint4*)&lt[n][q];
        *(uint4*)(whbt + (size_t)n * NN + m0 + q) = v;
    }
}

// ---------------- K2: flash-style masked-softmax @ Wh with bf16 MFMA ----------------
// B tile staged in LDS via coalesced loads (was: 64-line scattered global loads).
__global__ __launch_bounds__(256, 2) void k2_attn(
    const int* __restrict__ adj, const float* __restrict__ src, const float* __restrict__ dst,
    const u16* __restrict__ whbt, const u32* __restrict__ gmaxk,
    float* __restrict__ accp, float* __restrict__ lp)
{
    __shared__ u16 P[128][72];       // bf16 attention tile, +8 pad: frag reads <=2-way
    __shared__ u16 Bs[128][72];      // bf16 Wh^T tile [feature][k], same padded stride
    __shared__ float2 sC[128];       // (src_i*log2e, C_i*log2e)
    __shared__ float lred[128][16];
    const int t = threadIdx.x;
    const int i0 = blockIdx.x * 128;
    const int split = blockIdx.y;
    const int kb0 = split * KPER;
    const int lane = t & 63, wave = t >> 6;
    const int mw = (wave >> 1) * 64, nw = (wave & 1) * 64;
    const int l15 = lane & 15, quad = lane >> 4;
    const int g = t >> 4, c4 = (t & 15) * 4;

    if (t < 128) {
        float s = src[i0 + t] * L2E;
        float gm = funkey(*gmaxk) * L2E;
        float x = s + gm;
        sC[t] = make_float2(s, fmaxf(x, 0.01f * x));
    }
    float psum[8];
#pragma unroll
    for (int s2 = 0; s2 < 8; s2++) psum[s2] = 0.f;
    f32x4 acc[4][4];
#pragma unroll
    for (int mt = 0; mt < 4; mt++)
#pragma unroll
        for (int nt = 0; nt < 4; nt++) acc[mt][nt] = {0.f, 0.f, 0.f, 0.f};

    // prefetch iter 0: adj rows {16*s2+g} cols c4..c4+3; dst; B tile (4x uint4/thread)
    int4 av[8]; float4 dv; uint4 bv[4];
    {
        float4 d = *(const float4*)(dst + kb0 + c4);
        dv = make_float4(d.x * L2E, d.y * L2E, d.z * L2E, d.w * L2E);
    }
#pragma unroll
    for (int s2 = 0; s2 < 8; s2++)
        av[s2] = *(const int4*)(adj + (size_t)(i0 + 16 * s2 + g) * NN + kb0 + c4);
#pragma unroll
    for (int p = 0; p < 4; p++) {
        int f = p * 256 + t;          // 0..1023
        int n = f >> 3, seg = (f & 7) * 8;
        bv[p] = *(const uint4*)(whbt + (size_t)n * NN + kb0 + seg);
    }

    for (int it = 0; it < ITERS; ++it) {
        const int kb = kb0 + it * BK;
        __syncthreads();             // (A) prev MFMA done with P/Bs; iter0: sC ready
        float4 d4 = dv;
#pragma unroll
        for (int s2 = 0; s2 < 8; s2++) {
            int r = 16 * s2 + g;
            float2 sc = sC[r];
            int4 a4 = av[s2];
            float x0 = sc.x + d4.x; x0 = fmaxf(x0, 0.01f * x0);
            float x1 = sc.x + d4.y; x1 = fmaxf(x1, 0.01f * x1);
            float x2 = sc.x + d4.z; x2 = fmaxf(x2, 0.01f * x2);
            float x3 = sc.x + d4.w; x3 = fmaxf(x3, 0.01f * x3);
            float p0 = (a4.x > 0) ? exp2fast(x0 - sc.y) : 0.f;
            float p1 = (a4.y > 0) ? exp2fast(x1 - sc.y) : 0.f;
            float p2 = (a4.z > 0) ? exp2fast(x2 - sc.y) : 0.f;
            float p3 = (a4.w > 0) ? exp2fast(x3 - sc.y) : 0.f;
            psum[s2] += (p0 + p1) + (p2 + p3);
            u32 lo = (u32)f2bf(p0) | ((u32)f2bf(p1) << 16);
            u32 hi = (u32)f2bf(p2) | ((u32)f2bf(p3) << 16);
            *(uint2*)&P[r][c4] = make_uint2(lo, hi);
        }
#pragma unroll
        for (int p = 0; p < 4; p++) {
            int f = p * 256 + t;
            int n = f >> 3, seg = (f & 7) * 8;
            *(uint4*)&Bs[n][seg] = bv[p];
        }
        __syncthreads();             // (B) P/Bs visible
        if (it + 1 < ITERS) {        // prefetch next tiles under the MFMA
            int kbn = kb + BK;
            float4 d = *(const float4*)(dst + kbn + c4);
            dv = make_float4(d.x * L2E, d.y * L2E, d.z * L2E, d.w * L2E);
#pragma unroll
            for (int s2 = 0; s2 < 8; s2++)
                av[s2] = *(const int4*)(adj + (size_t)(i0 + 16 * s2 + g) * NN + kbn + c4);
#pragma unroll
            for (int p = 0; p < 4; p++) {
                int f = p * 256 + t;
                int n = f >> 3, seg = (f & 7) * 8;
                bv[p] = *(const uint4*)(whbt + (size_t)n * NN + kbn + seg);
            }
        }
#pragma unroll
        for (int ks = 0; ks < 2; ks++) {
            int kk = ks * 32 + quad * 8;
            short8 af[4], bfr[4];
#pragma unroll
            for (int mt = 0; mt < 4; mt++)
                af[mt] = *(const short8*)&P[mw + mt * 16 + l15][kk];
#pragma unroll
            for (int nt = 0; nt < 4; nt++)
                bfr[nt] = *(const short8*)&Bs[nw + nt * 16 + l15][kk];
#pragma unroll
            for (int mt = 0; mt < 4; mt++)
#pragma unroll
                for (int nt = 0; nt < 4; nt++)
                    acc[mt][nt] = __builtin_amdgcn_mfma_f32_16x16x32_bf16(
                        af[mt], bfr[nt], acc[mt][nt], 0, 0, 0);
        }
    }
    // row-sum partials
    __syncthreads();
#pragma unroll
    for (int s2 = 0; s2 < 8; s2++) lred[16 * s2 + g][t & 15] = psum[s2];
    __syncthreads();
    if (t < 128) {
        float s = 0.f;
#pragma unroll
        for (int j = 0; j < 16; j++) s += lred[t][j];
        lp[split * NN + i0 + t] = s;
    }
    // accumulator partials (C/D layout: col=lane&15, row=quad*4+reg)
    float* ab = accp + (size_t)split * (NN * FOUT);
#pragma unroll
    for (int mt = 0; mt < 4; mt++)
#pragma unroll
        for (int nt = 0; nt < 4; nt++) {
            int row = i0 + mw + mt * 16 + quad * 4;
            int col = nw + nt * 16 + l15;
#pragma unroll
            for (int reg = 0; reg < 4; reg++)
                ab[(size_t)(row + reg) * FOUT + col] = acc[mt][nt][reg];
        }
}

// ---------------- K3: combine splits, divide by row sums ---------------------------
__global__ __launch_bounds__(256) void k3_comb(
    const float* __restrict__ accp, const float* __restrict__ lp, float* __restrict__ out)
{
    int idx = blockIdx.x * 256 + threadIdx.x;   // float4 index, 0..262143
    int i = idx >> 5;                           // row
    float4 s = make_float4(0.f, 0.f, 0.f, 0.f);
    float l = 0.f;
#pragma unroll
    for (int sp = 0; sp < SPLITS; sp++) {
        float4 v = *(const float4*)(accp + (size_t)sp * (NN * FOUT) + (size_t)idx * 4);
        s.x += v.x; s.y += v.y; s.z += v.z; s.w += v.w;
        l += lp[sp * NN + i];
    }
    float inv = 1.0f / l;
    *(float4*)(out + (size_t)idx * 4) = make_float4(s.x * inv, s.y * inv, s.z * inv, s.w * inv);
}

extern "C" void kernel_launch(void* const* d_in, const int* in_sizes, int n_in,
                              void* d_out, int out_size, void* d_ws, size_t ws_size,
                              hipStream_t stream) {
    const float* h   = (const float*)d_in[0];
    const int*   adj = (const int*)d_in[1];
    const float* W   = (const float*)d_in[2];
    const float* a   = (const float*)d_in[3];
    float* out = (float*)d_out;

    char* ws = (char*)d_ws;
    u16*   whbt  = (u16*)ws;                            // 2 MB
    float* src   = (float*)(ws + (2u << 20));           // 32 KB
    float* dst   = src + NN;                            // 32 KB
    u32*   gmaxk = (u32*)(dst + NN);                    // 4 B
    float* accp  = (float*)(ws + (3u << 20));           // 32 MB
    float* lp    = (float*)(ws + (35u << 20));          // 256 KB

    (void)hipMemsetAsync(gmaxk, 0, sizeof(u32), stream);
    k1_wh<<<dim3(NN / 32), dim3(256), 0, stream>>>(h, W, a, whbt, src, dst, gmaxk);
    k2_attn<<<dim3(NN / 128, SPLITS), dim3(256), 0, stream>>>(adj, src, dst, whbt, gmaxk, accp, lp);
    k3_comb<<<dim3((NN * FOUT / 4) / 256), dim3(256), 0, stream>>>(accp, lp, out);
}

// Round 5
// 470.806 us; speedup vs baseline: 1.0245x; 1.0245x over previous
//
#include <hip/hip_runtime.h>
#include <hip/hip_bf16.h>

typedef unsigned short u16;
typedef unsigned int u32;
typedef __attribute__((ext_vector_type(8))) short short8;
typedef __attribute__((ext_vector_type(4))) float f32x4;

#define NN 8192
#define KIN 256
#define FOUT 128
#define SPLITS 8
#define KPER (NN / SPLITS)   // 1024
#define BK 64
#define ITERS (KPER / BK)    // 16
#define L2E 1.4426950408889634f

__device__ __forceinline__ float exp2fast(float x) { return __builtin_amdgcn_exp2f(x); }

__device__ __forceinline__ u16 f2bf(float f) {
    u32 u = __float_as_uint(f);
    u32 r = ((u >> 16) & 1u) + 0x7fffu;
    return (u16)((u + r) >> 16);
}
__device__ __forceinline__ u32 pk_bf16(float a, float b) {
    union { __hip_bfloat162 h2; u32 u; } cv;
    cv.h2 = __float22bfloat162_rn(make_float2(a, b));   // v_cvt_pk_bf16_f32
    return cv.u;
}
__device__ __forceinline__ u32 fkey(float f) {
    u32 b = __float_as_uint(f);
    return (b & 0x80000000u) ? ~b : (b | 0x80000000u);
}
__device__ __forceinline__ float funkey(u32 k) {
    u32 b = (k & 0x80000000u) ? (k & 0x7fffffffu) : ~k;
    return __uint_as_float(b);
}

// ---------------- K1: Wh = h@W (fp32 acc), Whbt (bf16 transposed), src/dst, gmax(dst)
__global__ __launch_bounds__(256) void k1_wh(
    const float* __restrict__ h, const float* __restrict__ W, const float* __restrict__ a,
    u16* __restrict__ whbt,
    float* __restrict__ src, float* __restrict__ dst, u32* __restrict__ gmaxk)
{
    __shared__ float hT[64][36];
    __shared__ u16   lt[128][40];
    __shared__ float sd[32][2];
    const int t  = threadIdx.x;
    const int m0 = blockIdx.x * 32;
    const int rq = t >> 5, cq = t & 31;

    float acc[4][4];
#pragma unroll
    for (int i = 0; i < 4; i++)
#pragma unroll
        for (int j = 0; j < 4; j++) acc[i][j] = 0.f;
    if (t < 64) sd[t >> 1][t & 1] = 0.f;

    for (int kt = 0; kt < KIN; kt += 64) {
        __syncthreads();
#pragma unroll
        for (int s2 = 0; s2 < 2; s2++) {
            int f = s2 * 256 + t;
            int r = f >> 4, kc = (f & 15) * 4;
            float4 hv = *(const float4*)(h + (size_t)(m0 + r) * KIN + kt + kc);
            hT[kc + 0][r] = hv.x; hT[kc + 1][r] = hv.y;
            hT[kc + 2][r] = hv.z; hT[kc + 3][r] = hv.w;
        }
        __syncthreads();
        for (int k = 0; k < 64; k++) {
            float4 wv = *(const float4*)(W + (size_t)(kt + k) * FOUT + cq * 4);
            float h0 = hT[k][rq * 4 + 0], h1 = hT[k][rq * 4 + 1];
            float h2 = hT[k][rq * 4 + 2], h3 = hT[k][rq * 4 + 3];
            acc[0][0] += h0 * wv.x; acc[0][1] += h0 * wv.y; acc[0][2] += h0 * wv.z; acc[0][3] += h0 * wv.w;
            acc[1][0] += h1 * wv.x; acc[1][1] += h1 * wv.y; acc[1][2] += h1 * wv.z; acc[1][3] += h1 * wv.w;
            acc[2][0] += h2 * wv.x; acc[2][1] += h2 * wv.y; acc[2][2] += h2 * wv.z; acc[2][3] += h2 * wv.w;
            acc[3][0] += h3 * wv.x; acc[3][1] += h3 * wv.y; acc[3][2] += h3 * wv.z; acc[3][3] += h3 * wv.w;
        }
    }
#pragma unroll
    for (int i = 0; i < 4; i++) {
        float sp = 0.f, dp = 0.f;
#pragma unroll
        for (int j = 0; j < 4; j++) {
            sp += acc[i][j] * a[cq * 4 + j];
            dp += acc[i][j] * a[FOUT + cq * 4 + j];
            lt[cq * 4 + j][rq * 4 + i] = f2bf(acc[i][j]);
        }
        atomicAdd(&sd[rq * 4 + i][0], sp);
        atomicAdd(&sd[rq * 4 + i][1], dp);
    }
    __syncthreads();
    if (t < 32) { src[m0 + t] = sd[t][0]; dst[m0 + t] = sd[t][1]; }
    if (t < 64) {
        float v = (t < 32) ? sd[t][1] : -3.0e38f;
#pragma unroll
        for (int off = 32; off >= 1; off >>= 1) v = fmaxf(v, __shfl_down(v, off));
        if (t == 0) atomicMax(gmaxk, fkey(v));
    }
#pragma unroll
    for (int s2 = 0; s2 < 2; s2++) {
        int f = s2 * 256 + t;
        int n = f >> 2;
        int q = (f & 3) * 8;
        uint4 v = *(const uint4*)&lt[n][q];
        *(uint4*)(whbt + (size_t)n * NN + m0 + q) = v;
    }
}

// ---------------- K2: flash-style masked-softmax @ Wh, 64-row tiles, high occupancy --
__global__ __launch_bounds__(256, 4) void k2_attn(
    const int* __restrict__ adj, const float* __restrict__ src, const float* __restrict__ dst,
    const u16* __restrict__ whbt, const u32* __restrict__ gmaxk,
    float* __restrict__ accp, float* __restrict__ lp)
{
    __shared__ u16 P[64][72];        // 9216 B  bf16 attention tile (A operand)
    __shared__ u16 Bs[128][72];      // 18432 B bf16 Wh^T tile [feature][k]
    __shared__ float2 sY[64];        // (y1 = s'-C', y2 = 0.01s'-C') per row
    const int t = threadIdx.x;
    const int bx = blockIdx.x;
    const int i0 = bx * 64;
    const int split = blockIdx.y;
    const int kb0 = split * KPER;
    const int lane = t & 63, wave = t >> 6;
    const int nw = wave * 32;        // each wave owns a 32-wide N strip
    const int l15 = lane & 15, quad = lane >> 4;
    const int g = t >> 4;            // row group 0..15
    const int c4 = (t & 15) * 4;     // col offset

    if (t < 64) {
        float s = src[i0 + t] * L2E;
        float gm = funkey(*gmaxk) * L2E;
        float x = s + gm;
        float C = fmaxf(x, 0.01f * x);
        sY[t] = make_float2(s - C, 0.01f * s - C);
    }
    float psum[4] = {0.f, 0.f, 0.f, 0.f};
    f32x4 acc[4][2];
#pragma unroll
    for (int mt = 0; mt < 4; mt++)
#pragma unroll
        for (int nt = 0; nt < 2; nt++) acc[mt][nt] = {0.f, 0.f, 0.f, 0.f};

    // staggered column windows: block bx starts at window (bx & 15)
    int itc = bx & (ITERS - 1);
    int4 av[4]; float4 d1, d2; uint4 bv[4];
    {
        int kb = kb0 + itc * BK;
        float4 d = *(const float4*)(dst + kb + c4);
        d1 = make_float4(d.x * L2E, d.y * L2E, d.z * L2E, d.w * L2E);
        d2 = make_float4(0.01f * d1.x, 0.01f * d1.y, 0.01f * d1.z, 0.01f * d1.w);
#pragma unroll
        for (int s2 = 0; s2 < 4; s2++)
            av[s2] = *(const int4*)(adj + (size_t)(i0 + 16 * s2 + g) * NN + kb + c4);
#pragma unroll
        for (int p = 0; p < 4; p++) {
            int f = p * 256 + t;
            int n = f >> 3, seg = (f & 7) * 8;
            bv[p] = *(const uint4*)(whbt + (size_t)n * NN + kb + seg);
        }
    }

    for (int it = 0; it < ITERS; ++it) {
        __syncthreads();             // (A) prev MFMA done with P/Bs; iter0: sY ready
#pragma unroll
        for (int s2 = 0; s2 < 4; s2++) {
            int r = 16 * s2 + g;
            float2 y = sY[r];
            int4 a4 = av[s2];
            float x0 = fmaxf(y.x + d1.x, y.y + d2.x);
            float x1 = fmaxf(y.x + d1.y, y.y + d2.y);
            float x2 = fmaxf(y.x + d1.z, y.y + d2.z);
            float x3 = fmaxf(y.x + d1.w, y.y + d2.w);
            x0 = (a4.x > 0) ? x0 : -1.0e9f;
            x1 = (a4.y > 0) ? x1 : -1.0e9f;
            x2 = (a4.z > 0) ? x2 : -1.0e9f;
            x3 = (a4.w > 0) ? x3 : -1.0e9f;
            float p0 = exp2fast(x0), p1 = exp2fast(x1);
            float p2 = exp2fast(x2), p3 = exp2fast(x3);
            psum[s2] += (p0 + p1) + (p2 + p3);
            *(uint2*)&P[r][c4] = make_uint2(pk_bf16(p0, p1), pk_bf16(p2, p3));
        }
#pragma unroll
        for (int p = 0; p < 4; p++) {
            int f = p * 256 + t;
            int n = f >> 3, seg = (f & 7) * 8;
            *(uint4*)&Bs[n][seg] = bv[p];
        }
        __syncthreads();             // (B) P/Bs visible
        if (it + 1 < ITERS) {        // prefetch next window under the MFMA
            int itn = (itc + 1) & (ITERS - 1);
            int kb = kb0 + itn * BK;
            float4 d = *(const float4*)(dst + kb + c4);
            d1 = make_float4(d.x * L2E, d.y * L2E, d.z * L2E, d.w * L2E);
            d2 = make_float4(0.01f * d1.x, 0.01f * d1.y, 0.01f * d1.z, 0.01f * d1.w);
#pragma unroll
            for (int s2 = 0; s2 < 4; s2++)
                av[s2] = *(const int4*)(adj + (size_t)(i0 + 16 * s2 + g) * NN + kb + c4);
#pragma unroll
            for (int p = 0; p < 4; p++) {
                int f = p * 256 + t;
                int n = f >> 3, seg = (f & 7) * 8;
                bv[p] = *(const uint4*)(whbt + (size_t)n * NN + kb + seg);
            }
            itc = itn;
        }
#pragma unroll
        for (int ks = 0; ks < 2; ks++) {
            int kk = ks * 32 + quad * 8;
            short8 af[4], bfr[2];
#pragma unroll
            for (int mt = 0; mt < 4; mt++)
                af[mt] = *(const short8*)&P[mt * 16 + l15][kk];
#pragma unroll
            for (int nt = 0; nt < 2; nt++)
                bfr[nt] = *(const short8*)&Bs[nw + nt * 16 + l15][kk];
#pragma unroll
            for (int mt = 0; mt < 4; mt++)
#pragma unroll
                for (int nt = 0; nt < 2; nt++)
                    acc[mt][nt] = __builtin_amdgcn_mfma_f32_16x16x32_bf16(
                        af[mt], bfr[nt], acc[mt][nt], 0, 0, 0);
        }
    }
    // row-sum partials: reduce across the 16 threads (same wave) covering each row
#pragma unroll
    for (int s2 = 0; s2 < 4; s2++) {
        float v = psum[s2];
        v += __shfl_down(v, 8, 16);
        v += __shfl_down(v, 4, 16);
        v += __shfl_down(v, 2, 16);
        v += __shfl_down(v, 1, 16);
        if ((t & 15) == 0) lp[split * NN + i0 + 16 * s2 + g] = v;
    }
    // accumulator partials, MFMA-native lane-major tile layout (fully coalesced)
    float* ab = accp + (size_t)split * (NN * FOUT);
#pragma unroll
    for (int mt = 0; mt < 4; mt++)
#pragma unroll
        for (int nt = 0; nt < 2; nt++) {
            int tm = bx * 4 + mt;          // global 16-row tile index
            int tn = wave * 2 + nt;        // global 16-col tile index
            *(f32x4*)&ab[(size_t)(tm * 8 + tn) * 256 + lane * 4] = acc[mt][nt];
        }
}

// ---------------- K2b: inverse row sums --------------------------------------------
__global__ __launch_bounds__(256) void k2b_rsum(const float* __restrict__ lp,
                                               float* __restrict__ rinv)
{
    int i = blockIdx.x * 256 + threadIdx.x;
    float s = 0.f;
#pragma unroll
    for (int sp = 0; sp < SPLITS; sp++) s += lp[sp * NN + i];
    rinv[i] = 1.0f / s;
}

// ---------------- K3: combine splits from tile layout, normalize, store ------------
__global__ __launch_bounds__(256) void k3_comb(
    const float* __restrict__ accp, const float* __restrict__ rinv, float* __restrict__ out)
{
    int idx = blockIdx.x * 256 + threadIdx.x;   // float4 index over tile storage
    int tile = idx >> 6, l = idx & 63;
    float4 s = make_float4(0.f, 0.f, 0.f, 0.f);
#pragma unroll
    for (int sp = 0; sp < SPLITS; sp++) {
        float4 v = *(const float4*)(accp + (size_t)sp * (NN * FOUT) + (size_t)idx * 4);
        s.x += v.x; s.y += v.y; s.z += v.z; s.w += v.w;
    }
    int row0 = (tile >> 3) * 16 + (l >> 4) * 4;
    int col  = (tile & 7) * 16 + (l & 15);
    float4 ri = *(const float4*)(rinv + row0);
    out[(size_t)(row0 + 0) * FOUT + col] = s.x * ri.x;
    out[(size_t)(row0 + 1) * FOUT + col] = s.y * ri.y;
    out[(size_t)(row0 + 2) * FOUT + col] = s.z * ri.z;
    out[(size_t)(row0 + 3) * FOUT + col] = s.w * ri.w;
}

extern "C" void kernel_launch(void* const* d_in, const int* in_sizes, int n_in,
                              void* d_out, int out_size, void* d_ws, size_t ws_size,
                              hipStream_t stream) {
    const float* h   = (const float*)d_in[0];
    const int*   adj = (const int*)d_in[1];
    const float* W   = (const float*)d_in[2];
    const float* a   = (const float*)d_in[3];
    float* out = (float*)d_out;

    char* ws = (char*)d_ws;
    u16*   whbt  = (u16*)ws;                            // 2 MB
    float* src   = (float*)(ws + (2u << 20));           // 32 KB
    float* dst   = src + NN;                            // 32 KB
    u32*   gmaxk = (u32*)(dst + NN);                    // 4 B
    float* accp  = (float*)(ws + (3u << 20));           // 32 MB
    float* lp    = (float*)(ws + (35u << 20));          // 256 KB
    float* rinv  = (float*)(ws + (36u << 20));          // 32 KB

    (void)hipMemsetAsync(gmaxk, 0, sizeof(u32), stream);
    k1_wh<<<dim3(NN / 32), dim3(256), 0, stream>>>(h, W, a, whbt, src, dst, gmaxk);
    k2_attn<<<dim3(NN / 64, SPLITS), dim3(256), 0, stream>>>(adj, src, dst, whbt, gmaxk, accp, lp);
    k2b_rsum<<<dim3(NN / 256), dim3(256), 0, stream>>>(lp, rinv);
    k3_comb<<<dim3((NN * FOUT / 4) / 256), dim3(256), 0, stream>>>(accp, rinv, out);
}

// Round 6
// 445.784 us; speedup vs baseline: 1.0820x; 1.0561x over previous
//
#include <hip/hip_runtime.h>
#include <hip/hip_bf16.h>

typedef unsigned short u16;
typedef unsigned int u32;
typedef __attribute__((ext_vector_type(8))) short short8;
typedef __attribute__((ext_vector_type(4))) float f32x4;

#define NN 8192
#define KIN 256
#define FOUT 128
#define SPLITS 8
#define KPER (NN / SPLITS)   // 1024
#define KSTEPS (KPER / 32)   // 32 k-steps of 32 per split
#define L2E 1.4426950408889634f

__device__ __forceinline__ float exp2fast(float x) { return __builtin_amdgcn_exp2f(x); }

__device__ __forceinline__ u16 f2bf(float f) {
    u32 u = __float_as_uint(f);
    u32 r = ((u >> 16) & 1u) + 0x7fffu;
    return (u16)((u + r) >> 16);
}
__device__ __forceinline__ u32 pk_bf16(float a, float b) {
    union { __hip_bfloat162 h2; u32 u; } cv;
    cv.h2 = __float22bfloat162_rn(make_float2(a, b));   // v_cvt_pk_bf16_f32
    return cv.u;
}
__device__ __forceinline__ u32 fkey(float f) {
    u32 b = __float_as_uint(f);
    return (b & 0x80000000u) ? ~b : (b | 0x80000000u);
}
__device__ __forceinline__ float funkey(u32 k) {
    u32 b = (k & 0x80000000u) ? (k & 0x7fffffffu) : ~k;
    return __uint_as_float(b);
}

// ---------------- K1: Wh = h@W (fp32 acc) -> whfrag (B-fragment-major bf16), src, dst*log2e, gmax
// whfrag layout: [(kstep*8 + ntile)*64 + lane] * 8 u16, element j = Wh[kstep*32 + (lane>>4)*8 + j][ntile*16 + (lane&15)]
__global__ __launch_bounds__(256) void k1_wh(
    const float* __restrict__ h, const float* __restrict__ W, const float* __restrict__ a,
    u16* __restrict__ whfrag,
    float* __restrict__ src, float* __restrict__ dl2e, u32* __restrict__ gmaxk)
{
    __shared__ float hT[64][36];
    __shared__ u16   lt[128][40];    // [feature][node] bf16 tile, 80B row stride
    __shared__ float sd[32][2];
    const int t  = threadIdx.x;
    const int m0 = blockIdx.x * 32;  // node block; kstep = blockIdx.x
    const int rq = t >> 5, cq = t & 31;

    float acc[4][4];
#pragma unroll
    for (int i = 0; i < 4; i++)
#pragma unroll
        for (int j = 0; j < 4; j++) acc[i][j] = 0.f;
    if (t < 64) sd[t >> 1][t & 1] = 0.f;

    for (int kt = 0; kt < KIN; kt += 64) {
        __syncthreads();
#pragma unroll
        for (int s2 = 0; s2 < 2; s2++) {
            int f = s2 * 256 + t;
            int r = f >> 4, kc = (f & 15) * 4;
            float4 hv = *(const float4*)(h + (size_t)(m0 + r) * KIN + kt + kc);
            hT[kc + 0][r] = hv.x; hT[kc + 1][r] = hv.y;
            hT[kc + 2][r] = hv.z; hT[kc + 3][r] = hv.w;
        }
        __syncthreads();
        for (int k = 0; k < 64; k++) {
            float4 wv = *(const float4*)(W + (size_t)(kt + k) * FOUT + cq * 4);
            float h0 = hT[k][rq * 4 + 0], h1 = hT[k][rq * 4 + 1];
            float h2 = hT[k][rq * 4 + 2], h3 = hT[k][rq * 4 + 3];
            acc[0][0] += h0 * wv.x; acc[0][1] += h0 * wv.y; acc[0][2] += h0 * wv.z; acc[0][3] += h0 * wv.w;
            acc[1][0] += h1 * wv.x; acc[1][1] += h1 * wv.y; acc[1][2] += h1 * wv.z; acc[1][3] += h1 * wv.w;
            acc[2][0] += h2 * wv.x; acc[2][1] += h2 * wv.y; acc[2][2] += h2 * wv.z; acc[2][3] += h2 * wv.w;
            acc[3][0] += h3 * wv.x; acc[3][1] += h3 * wv.y; acc[3][2] += h3 * wv.z; acc[3][3] += h3 * wv.w;
        }
    }
#pragma unroll
    for (int i = 0; i < 4; i++) {
        float sp = 0.f, dp = 0.f;
#pragma unroll
        for (int j = 0; j < 4; j++) {
            sp += acc[i][j] * a[cq * 4 + j];
            dp += acc[i][j] * a[FOUT + cq * 4 + j];
            lt[cq * 4 + j][rq * 4 + i] = f2bf(acc[i][j]);
        }
        atomicAdd(&sd[rq * 4 + i][0], sp);
        atomicAdd(&sd[rq * 4 + i][1], dp);
    }
    __syncthreads();
    if (t < 32) { src[m0 + t] = sd[t][0]; dl2e[m0 + t] = sd[t][1] * L2E; }
    if (t < 64) {
        float v = (t < 32) ? sd[t][1] : -3.0e38f;
#pragma unroll
        for (int off = 32; off >= 1; off >>= 1) v = fmaxf(v, __shfl_down(v, off));
        if (t == 0) atomicMax(gmaxk, fkey(v));
    }
    // fragment-major write: 8 ntiles x 64 lanes x 16B, fully coalesced
    const int kstep = blockIdx.x;
#pragma unroll
    for (int p = 0; p < 2; p++) {
        int f = p * 256 + t;         // 0..511
        int nt = f >> 6;             // 0..7
        int l  = f & 63;
        short8 v = *(const short8*)&lt[nt * 16 + (l & 15)][(l >> 4) * 8];
        *(short8*)(whfrag + ((size_t)(kstep * 8 + nt) * 64 + l) * 8) = v;
    }
}

// ---------------- K2: barrier-free flash attention; wave = 16-row strip, no LDS -----
__global__ __launch_bounds__(256, 4) void k2_attn(
    const int* __restrict__ adj, const float* __restrict__ src, const float* __restrict__ dl2e,
    const u16* __restrict__ whfrag, const u32* __restrict__ gmaxk,
    float* __restrict__ accp, float* __restrict__ lp)
{
    const int t = threadIdx.x;
    const int lane = t & 63, wave = t >> 6;
    const int strip = blockIdx.x * 4 + wave;     // 0..511 (16-row m-tile)
    const int i0 = strip * 16;
    const int split = blockIdx.y;
    const int l15 = lane & 15;
    const int kq = (lane >> 4) * 8;              // this lane's k offset within a 32-step

    float sp = src[i0 + l15] * L2E;
    float gm = funkey(*gmaxk) * L2E;
    float xx = sp + gm;
    float C = fmaxf(xx, 0.01f * xx);
    const float y1 = sp - C, y2 = 0.01f * sp - C;

    const int* arow = adj + (size_t)(i0 + l15) * NN;     // lane's adj row
    const int st0 = blockIdx.x & (KSTEPS - 1);           // stagger windows across blocks
    const int kbase = split * KPER;

    f32x4 acc[8];
#pragma unroll
    for (int nt = 0; nt < 8; nt++) acc[nt] = {0.f, 0.f, 0.f, 0.f};
    float psum = 0.f;

    // depth-2 register prefetch of adj + dst (no barriers anywhere -> loads stay in flight)
    int4 aL[2], aH[2]; float4 dL[2], dH[2];
#pragma unroll
    for (int s = 0; s < 2; s++) {
        int kb = kbase + ((st0 + s) & (KSTEPS - 1)) * 32;
        aL[s] = *(const int4*)(arow + kb + kq);
        aH[s] = *(const int4*)(arow + kb + kq + 4);
        dL[s] = *(const float4*)(dl2e + kb + kq);
        dH[s] = *(const float4*)(dl2e + kb + kq + 4);
    }

#pragma unroll 4
    for (int it = 0; it < KSTEPS; ++it) {
        const int sl = it & 1;
        const int kb = kbase + ((st0 + it) & (KSTEPS - 1)) * 32;

        // B fragments: contiguous 1KB/wave per tile, L2-resident
        uint4 bv[8];
        const u16* wf = whfrag + ((size_t)(kb >> 5) * 8 * 64 + lane) * 8;
#pragma unroll
        for (int nt = 0; nt < 8; nt++)
            bv[nt] = *(const uint4*)(wf + (size_t)nt * 64 * 8);

        // P in A-fragment layout (row = l15, k = kq + j), lane-private
        int4 al = aL[sl], ah = aH[sl];
        float4 dl = dL[sl], dh = dH[sl];
        float p0, p1, p2, p3, p4, p5, p6, p7;
        {
            float x;
            x = fmaxf(y1 + dl.x, y2 + 0.01f * dl.x); p0 = exp2fast(al.x > 0 ? x : -1.0e9f);
            x = fmaxf(y1 + dl.y, y2 + 0.01f * dl.y); p1 = exp2fast(al.y > 0 ? x : -1.0e9f);
            x = fmaxf(y1 + dl.z, y2 + 0.01f * dl.z); p2 = exp2fast(al.z > 0 ? x : -1.0e9f);
            x = fmaxf(y1 + dl.w, y2 + 0.01f * dl.w); p3 = exp2fast(al.w > 0 ? x : -1.0e9f);
            x = fmaxf(y1 + dh.x, y2 + 0.01f * dh.x); p4 = exp2fast(ah.x > 0 ? x : -1.0e9f);
            x = fmaxf(y1 + dh.y, y2 + 0.01f * dh.y); p5 = exp2fast(ah.y > 0 ? x : -1.0e9f);
            x = fmaxf(y1 + dh.z, y2 + 0.01f * dh.z); p6 = exp2fast(ah.z > 0 ? x : -1.0e9f);
            x = fmaxf(y1 + dh.w, y2 + 0.01f * dh.w); p7 = exp2fast(ah.w > 0 ? x : -1.0e9f);
        }
        psum += ((p0 + p1) + (p2 + p3)) + ((p4 + p5) + (p6 + p7));
        union { short8 s8; u32 u[4]; } af;
        af.u[0] = pk_bf16(p0, p1); af.u[1] = pk_bf16(p2, p3);
        af.u[2] = pk_bf16(p4, p5); af.u[3] = pk_bf16(p6, p7);

        // prefetch it+2 into this slot (wrapped index: always valid, branchless)
        {
            int kb2 = kbase + ((st0 + it + 2) & (KSTEPS - 1)) * 32;
            aL[sl] = *(const int4*)(arow + kb2 + kq);
            aH[sl] = *(const int4*)(arow + kb2 + kq + 4);
            dL[sl] = *(const float4*)(dl2e + kb2 + kq);
            dH[sl] = *(const float4*)(dl2e + kb2 + kq + 4);
        }

#pragma unroll
        for (int nt = 0; nt < 8; nt++) {
            union { uint4 q; short8 s8; } bf; bf.q = bv[nt];
            acc[nt] = __builtin_amdgcn_mfma_f32_16x16x32_bf16(af.s8, bf.s8, acc[nt], 0, 0, 0);
        }
    }

    // row sums: reduce over the 4 quads holding each row
    float v = psum;
    v += __shfl_down(v, 32);
    v += __shfl_down(v, 16);
    if (lane < 16) lp[split * NN + i0 + lane] = v;

    // accumulator partials, lane-major tile layout (fully coalesced)
    float* ab = accp + (size_t)split * (NN * FOUT);
#pragma unroll
    for (int nt = 0; nt < 8; nt++)
        *(f32x4*)&ab[((size_t)(strip * 8 + nt) * 64 + lane) * 4] = acc[nt];
}

// ---------------- K2b: inverse row sums --------------------------------------------
__global__ __launch_bounds__(256) void k2b_rsum(const float* __restrict__ lp,
                                               float* __restrict__ rinv)
{
    int i = blockIdx.x * 256 + threadIdx.x;
    float s = 0.f;
#pragma unroll
    for (int sp = 0; sp < SPLITS; sp++) s += lp[sp * NN + i];
    rinv[i] = 1.0f / s;
}

// ---------------- K3: combine splits from tile layout, normalize, store ------------
__global__ __launch_bounds__(256) void k3_comb(
    const float* __restrict__ accp, const float* __restrict__ rinv, float* __restrict__ out)
{
    int idx = blockIdx.x * 256 + threadIdx.x;   // float4 index over tile storage
    int tile = idx >> 6, l = idx & 63;
    float4 s = make_float4(0.f, 0.f, 0.f, 0.f);
#pragma unroll
    for (int sp = 0; sp < SPLITS; sp++) {
        float4 v = *(const float4*)(accp + (size_t)sp * (NN * FOUT) + (size_t)idx * 4);
        s.x += v.x; s.y += v.y; s.z += v.z; s.w += v.w;
    }
    int row0 = (tile >> 3) * 16 + (l >> 4) * 4;
    int col  = (tile & 7) * 16 + (l & 15);
    float4 ri = *(const float4*)(rinv + row0);
    out[(size_t)(row0 + 0) * FOUT + col] = s.x * ri.x;
    out[(size_t)(row0 + 1) * FOUT + col] = s.y * ri.y;
    out[(size_t)(row0 + 2) * FOUT + col] = s.z * ri.z;
    out[(size_t)(row0 + 3) * FOUT + col] = s.w * ri.w;
}

extern "C" void kernel_launch(void* const* d_in, const int* in_sizes, int n_in,
                              void* d_out, int out_size, void* d_ws, size_t ws_size,
                              hipStream_t stream) {
    const float* h   = (const float*)d_in[0];
    const int*   adj = (const int*)d_in[1];
    const float* W   = (const float*)d_in[2];
    const float* a   = (const float*)d_in[3];
    float* out = (float*)d_out;

    char* ws = (char*)d_ws;
    u16*   whfrag = (u16*)ws;                           // 2 MB
    float* src    = (float*)(ws + (2u << 20));          // 32 KB
    float* dl2e   = src + NN;                           // 32 KB
    u32*   gmaxk  = (u32*)(dl2e + NN);                  // 4 B
    float* accp   = (float*)(ws + (3u << 20));          // 32 MB
    float* lp     = (float*)(ws + (35u << 20));         // 256 KB
    float* rinv   = (float*)(ws + (36u << 20));         // 32 KB

    (void)hipMemsetAsync(gmaxk, 0, sizeof(u32), stream);
    k1_wh<<<dim3(NN / 32), dim3(256), 0, stream>>>(h, W, a, whfrag, src, dl2e, gmaxk);
    k2_attn<<<dim3(NN / 64, SPLITS), dim3(256), 0, stream>>>(adj, src, dl2e, whfrag, gmaxk, accp, lp);
    k2b_rsum<<<dim3(NN / 256), dim3(256), 0, stream>>>(lp, rinv);
    k3_comb<<<dim3((NN * FOUT / 4) / 256), dim3(256), 0, stream>>>(accp, rinv, out);
}